// Round 1
// baseline (879.894 us; speedup 1.0000x reference)
//
#include <hip/hip_runtime.h>
#include <hip/hip_bf16.h>

typedef _Float16 f16x8 __attribute__((ext_vector_type(8)));
typedef float f32x4 __attribute__((ext_vector_type(4)));

#define BQ_TOTAL 65536      // B*Q = 8*8192
#define KPAD0 640           // 596 padded to multiple of 64
#define HID 256
#define NOUT 27

// ---------------- weight transpose+cast: wt[n*Kpad+k] = w[k*Nin+n] ----------
__global__ void transpose_cast(const float* __restrict__ w, _Float16* __restrict__ wt,
                               int Kin, int Nin, int Kpad, int Npad) {
    int idx = blockIdx.x * 256 + threadIdx.x;
    if (idx >= Npad * Kpad) return;
    int n = idx / Kpad, k = idx - n * Kpad;
    float v = (n < Nin && k < Kin) ? w[k * Nin + n] : 0.f;
    wt[idx] = (_Float16)v;
}

// ---------------- gather: build X rows (640 f16) + areas --------------------
__global__ __launch_bounds__(256) void gather_kernel(
    const float* __restrict__ feat, const float* __restrict__ coord,
    const float* __restrict__ cell, _Float16* __restrict__ X,
    float* __restrict__ areas, int s)
{
    int wave = threadIdx.x >> 6, lane = threadIdx.x & 63;
    int row = blockIdx.x * 4 + wave;          // 0..65535 (b*8192+q)
    int b = row >> 13;
    const float* cp = coord + (size_t)row * 18;
    float cx = cp[8], cy = cp[9];
    float vx = (s & 2) ? 1.f : -1.f, vy = (s & 1) ? 1.f : -1.f;
    const float rx = 1.f / 48.f;
    cx += vx * rx + 1e-6f;
    cy += vy * rx + 1e-6f;
    cx = fminf(fmaxf(cx, -1.f + 1e-6f), 1.f - 1e-6f);
    cy = fminf(fmaxf(cy, -1.f + 1e-6f), 1.f - 1e-6f);
    int ri = (int)rintf((cx + 1.f) * 24.f - 0.5f); ri = min(max(ri, 0), 47);
    int ci = (int)rintf((cy + 1.f) * 24.f - 0.5f); ci = min(max(ci, 0), 47);
    float qx = (float)(2 * ri + 1) / 48.f - 1.f;
    float qy = (float)(2 * ci + 1) / 48.f - 1.f;

    _Float16* xr = X + (size_t)row * KPAD0;
    const float* fb = feat + (size_t)b * 64 * 48 * 48;
    #pragma unroll
    for (int it = 0; it < 10; it++) {
        int e = lane + it * 64;
        float v;
        if (e < 576) {
            int c = e / 9, k = e - c * 9;
            int di = k / 3 - 1, dj = k - (k / 3) * 3 - 1;
            int r2 = ri + di, c2 = ci + dj;
            v = ((unsigned)r2 < 48u && (unsigned)c2 < 48u) ? fb[(c * 48 + r2) * 48 + c2] : 0.f;
        } else if (e < 594) {
            int p = (e - 576) >> 1, comp = (e - 576) & 1;
            float cpv = cp[p * 2 + comp];
            v = comp ? (cpv - qy) : ((cpv - qx) * 2304.f);
        } else if (e == 594) {
            v = cell[(size_t)row * 2 + 0] * 48.f;
        } else if (e == 595) {
            v = cell[(size_t)row * 2 + 1] * 48.f;
        } else {
            v = 0.f;
        }
        xr[e] = (_Float16)v;
    }
    if (lane == 0) {
        float r0x = (cp[0] - qx) * 2304.f;
        float r0y = (cp[1] - qy);
        areas[s * BQ_TOTAL + row] = fabsf(r0x * r0y) + 1e-9f;
    }
}

// ---------------- GEMM: C(M,N) = act(A(M,K) @ Bt(N,K)^T + bias) -------------
// 128x128 tile, BK=64, 256 threads = 4 waves, each wave 64x64 via 4x4 mfma16x16x32
template<bool RELU, typename OutT>
__global__ __launch_bounds__(256) void gemm_kernel(
    const _Float16* __restrict__ A, const _Float16* __restrict__ Bt,
    const float* __restrict__ bias, OutT* __restrict__ C,
    int Nout, int K, int ldc)
{
    __shared__ _Float16 As[128 * 64];
    __shared__ _Float16 Bs[128 * 64];
    int m0 = blockIdx.x * 128;
    int n0 = blockIdx.y * 128;
    int t = threadIdx.x;
    int wave = t >> 6, lane = t & 63;
    int wr = wave >> 1, wc = wave & 1;
    int lrow = lane & 15, lq = lane >> 4;

    f32x4 acc[4][4] = {};

    for (int k0 = 0; k0 < K; k0 += 64) {
        __syncthreads();
        #pragma unroll
        for (int i = 0; i < 4; i++) {
            int chunk = t + i * 256;
            int r = chunk >> 3, cc = (chunk & 7) * 8;
            *(int4*)&As[r * 64 + cc] = *(const int4*)&A[(size_t)(m0 + r) * K + k0 + cc];
            *(int4*)&Bs[r * 64 + cc] = *(const int4*)&Bt[(size_t)(n0 + r) * K + k0 + cc];
        }
        __syncthreads();
        #pragma unroll
        for (int kk = 0; kk < 64; kk += 32) {
            f16x8 af[4], bf[4];
            #pragma unroll
            for (int mi = 0; mi < 4; mi++)
                af[mi] = *(const f16x8*)&As[(wr * 64 + mi * 16 + lrow) * 64 + kk + lq * 8];
            #pragma unroll
            for (int ni = 0; ni < 4; ni++)
                bf[ni] = *(const f16x8*)&Bs[(wc * 64 + ni * 16 + lrow) * 64 + kk + lq * 8];
            #pragma unroll
            for (int mi = 0; mi < 4; mi++)
                #pragma unroll
                for (int ni = 0; ni < 4; ni++)
                    acc[mi][ni] = __builtin_amdgcn_mfma_f32_16x16x32_f16(
                        af[mi], bf[ni], acc[mi][ni], 0, 0, 0);
        }
    }

    #pragma unroll
    for (int mi = 0; mi < 4; mi++) {
        int row = m0 + wr * 64 + mi * 16 + lq * 4;
        #pragma unroll
        for (int ni = 0; ni < 4; ni++) {
            int col = n0 + wc * 64 + ni * 16 + lrow;
            if (col < Nout) {
                float bv = bias[col];
                #pragma unroll
                for (int r = 0; r < 4; r++) {
                    float v = acc[mi][ni][r] + bv;
                    if (RELU) v = v > 0.f ? v : 0.f;
                    C[(size_t)(row + r) * ldc + col] = (OutT)v;
                }
            }
        }
    }
}

// ---------------- combine: out = sum_s pred_s * (area_swap(s)/tot) ----------
__global__ void combine_kernel(const float* __restrict__ preds,
                               const float* __restrict__ areas,
                               float* __restrict__ out) {
    int idx = blockIdx.x * 256 + threadIdx.x;
    if (idx >= BQ_TOTAL * NOUT) return;
    int bq = idx / NOUT, o = idx - bq * NOUT;
    float a0 = areas[bq];
    float a1 = areas[BQ_TOTAL + bq];
    float a2 = areas[2 * BQ_TOTAL + bq];
    float a3 = areas[3 * BQ_TOTAL + bq];
    float tot = a0 + a1 + a2 + a3;
    size_t stride = (size_t)BQ_TOTAL * NOUT;
    float r = preds[0 * stride + (size_t)bq * NOUT + o] * a3
            + preds[1 * stride + (size_t)bq * NOUT + o] * a2
            + preds[2 * stride + (size_t)bq * NOUT + o] * a1
            + preds[3 * stride + (size_t)bq * NOUT + o] * a0;
    out[idx] = r / tot;
}

extern "C" void kernel_launch(void* const* d_in, const int* in_sizes, int n_in,
                              void* d_out, int out_size, void* d_ws, size_t ws_size,
                              hipStream_t stream) {
    const float* feat  = (const float*)d_in[0];
    const float* coord = (const float*)d_in[1];
    const float* cell  = (const float*)d_in[2];
    const float* w0 = (const float*)d_in[3];  const float* b0 = (const float*)d_in[4];
    const float* w1 = (const float*)d_in[5];  const float* b1 = (const float*)d_in[6];
    const float* w2 = (const float*)d_in[7];  const float* b2 = (const float*)d_in[8];
    const float* w3 = (const float*)d_in[9];  const float* b3 = (const float*)d_in[10];
    const float* w4 = (const float*)d_in[11]; const float* b4 = (const float*)d_in[12];
    float* out = (float*)d_out;

    char* ws = (char*)d_ws;
    size_t off = 0;
    _Float16* W0t = (_Float16*)(ws + off); off += (size_t)256 * KPAD0 * 2;   // 327680
    _Float16* W1t = (_Float16*)(ws + off); off += (size_t)256 * 256 * 2;
    _Float16* W2t = (_Float16*)(ws + off); off += (size_t)256 * 256 * 2;
    _Float16* W3t = (_Float16*)(ws + off); off += (size_t)256 * 256 * 2;
    _Float16* W4t = (_Float16*)(ws + off); off += (size_t)128 * 256 * 2;     // padded to 128 rows
    float* areas  = (float*)(ws + off);    off += (size_t)4 * BQ_TOTAL * 4;
    float* preds  = (float*)(ws + off);    off += (size_t)4 * BQ_TOTAL * NOUT * 4;
    _Float16* X   = (_Float16*)(ws + off); off += (size_t)BQ_TOTAL * KPAD0 * 2;
    _Float16* H0  = (_Float16*)(ws + off); off += (size_t)BQ_TOTAL * HID * 2;
    _Float16* H1  = (_Float16*)(ws + off); off += (size_t)BQ_TOTAL * HID * 2;

    // weights -> transposed f16 (re-done every call; inputs are re-poisoned)
    {
        int n;
        n = 256 * KPAD0; transpose_cast<<<(n + 255) / 256, 256, 0, stream>>>(w0, W0t, 596, 256, KPAD0, 256);
        n = 256 * 256;   transpose_cast<<<(n + 255) / 256, 256, 0, stream>>>(w1, W1t, 256, 256, 256, 256);
        n = 256 * 256;   transpose_cast<<<(n + 255) / 256, 256, 0, stream>>>(w2, W2t, 256, 256, 256, 256);
        n = 256 * 256;   transpose_cast<<<(n + 255) / 256, 256, 0, stream>>>(w3, W3t, 256, 256, 256, 256);
        n = 128 * 256;   transpose_cast<<<(n + 255) / 256, 256, 0, stream>>>(w4, W4t, 256, NOUT, 256, 128);
    }

    for (int s = 0; s < 4; s++) {
        gather_kernel<<<BQ_TOTAL / 4, 256, 0, stream>>>(feat, coord, cell, X, areas, s);
        gemm_kernel<true, _Float16><<<dim3(BQ_TOTAL / 128, 2), 256, 0, stream>>>(
            X, W0t, b0, H0, 256, KPAD0, 256);
        gemm_kernel<true, _Float16><<<dim3(BQ_TOTAL / 128, 2), 256, 0, stream>>>(
            H0, W1t, b1, H1, 256, 256, 256);
        gemm_kernel<true, _Float16><<<dim3(BQ_TOTAL / 128, 2), 256, 0, stream>>>(
            H1, W2t, b2, H0, 256, 256, 256);
        gemm_kernel<true, _Float16><<<dim3(BQ_TOTAL / 128, 2), 256, 0, stream>>>(
            H0, W3t, b3, H1, 256, 256, 256);
        gemm_kernel<false, float><<<dim3(BQ_TOTAL / 128, 1), 256, 0, stream>>>(
            H1, W4t, b4, preds + (size_t)s * BQ_TOTAL * NOUT, NOUT, 256, NOUT);
    }

    combine_kernel<<<(BQ_TOTAL * NOUT + 255) / 256, 256, 0, stream>>>(preds, areas, out);
}

// Round 2
// 869.715 us; speedup vs baseline: 1.0117x; 1.0117x over previous
//
#include <hip/hip_runtime.h>
#include <hip/hip_bf16.h>

typedef _Float16 f16x8 __attribute__((ext_vector_type(8)));
typedef float f32x4 __attribute__((ext_vector_type(4)));

#define BQ 65536            // B*Q = 8*8192
#define KPAD0 640           // 596 padded to multiple of 64
#define HID 256
#define NOUT 27

// XOR-swizzle: permute 16B (8-f16) groups within a 64-f16 row by row&7.
// Breaks the stride-128B row aliasing (16-way bank conflict -> 2-way free).
__device__ __forceinline__ int swz(int r, int c) {
    return ((((c) >> 3) ^ ((r) & 7)) << 3) | ((c) & 7);
}

// ---------------- weight transpose+cast: wt[n*Kpad+k] = w[k*Nin+n] ----------
__global__ void transpose_cast(const float* __restrict__ w, _Float16* __restrict__ wt,
                               int Kin, int Nin, int Kpad, int Npad) {
    int idx = blockIdx.x * 256 + threadIdx.x;
    if (idx >= Npad * Kpad) return;
    int n = idx / Kpad, k = idx - n * Kpad;
    float v = (n < Nin && k < Kin) ? w[k * Nin + n] : 0.f;
    wt[idx] = (_Float16)v;
}

// ---------------- fused gather + GEMM layer0 --------------------------------
// Block: 256 thr = 4 waves, tile 64 rows x 256 cols (full N), BK=64.
// A-tile built in LDS directly from feat/coord/cell (no X materialization).
// blocks_per_shift = 1024 (64 rows each); s = s_base + (blk>>10).
__global__ __launch_bounds__(256) void fused_gemm0(
    const float* __restrict__ feat, const float* __restrict__ coord,
    const float* __restrict__ cell, const _Float16* __restrict__ W0t,
    const float* __restrict__ bias, float* __restrict__ areas,
    _Float16* __restrict__ H, int s_base)
{
    __shared__ _Float16 As[64 * 64];
    __shared__ _Float16 Bs[256 * 64];
    __shared__ int   rc_s[64 * 2];
    __shared__ float q_s[64 * 2];

    int t = threadIdx.x;
    int blk = blockIdx.x;
    int s = s_base + (blk >> 10);
    int bq0 = (blk & 1023) * 64;

    if (t < 64) {
        int bq = bq0 + t;
        const float* cp = coord + (size_t)bq * 18;
        float cx = cp[8], cy = cp[9];
        float vx = (s & 2) ? 1.f : -1.f, vy = (s & 1) ? 1.f : -1.f;
        cx += vx * (1.f / 48.f) + 1e-6f;
        cy += vy * (1.f / 48.f) + 1e-6f;
        cx = fminf(fmaxf(cx, -1.f + 1e-6f), 1.f - 1e-6f);
        cy = fminf(fmaxf(cy, -1.f + 1e-6f), 1.f - 1e-6f);
        int ri = (int)rintf((cx + 1.f) * 24.f - 0.5f); ri = min(max(ri, 0), 47);
        int ci = (int)rintf((cy + 1.f) * 24.f - 0.5f); ci = min(max(ci, 0), 47);
        float qx = (float)(2 * ri + 1) / 48.f - 1.f;
        float qy = (float)(2 * ci + 1) / 48.f - 1.f;
        rc_s[t * 2] = ri; rc_s[t * 2 + 1] = ci;
        q_s[t * 2] = qx;  q_s[t * 2 + 1] = qy;
        float r0x = (cp[0] - qx) * 2304.f;
        float r0y = (cp[1] - qy);
        areas[s * BQ + bq] = fabsf(r0x * r0y) + 1e-9f;
    }
    __syncthreads();

    int wave = t >> 6, lane = t & 63;     // wave = n-block 0..3, rows shared
    int lrow = lane & 15, lq = lane >> 4;
    f32x4 acc[4][4] = {};

    // staging assignment: thread t builds row r = t>>2, cols (t&3)*16 .. +15
    int r = t >> 2;
    int c0 = (t & 3) * 16;
    int bq = bq0 + r;
    int b = bq >> 13;
    const float* cp = coord + (size_t)bq * 18;
    const float* fb = feat + (size_t)b * 64 * 48 * 48;
    const float* cl = cell + (size_t)bq * 2;
    int ri = rc_s[r * 2], ci = rc_s[r * 2 + 1];
    float qx = q_s[r * 2], qy = q_s[r * 2 + 1];

    for (int k0 = 0; k0 < KPAD0; k0 += 64) {
        __syncthreads();
        // ---- build A tile (gather) ----
        _Float16 tmp[16];
        #pragma unroll
        for (int j = 0; j < 16; j++) {
            int e = k0 + c0 + j;
            float v;
            if (e < 576) {
                int ch = e / 9, k = e - ch * 9;
                int di = k / 3 - 1, dj = k - (k / 3) * 3 - 1;
                int r2 = ri + di, c2 = ci + dj;
                v = ((unsigned)r2 < 48u && (unsigned)c2 < 48u)
                        ? fb[(ch * 48 + r2) * 48 + c2] : 0.f;
            } else if (e < 594) {
                int p = (e - 576) >> 1;
                v = ((e - 576) & 1) ? (cp[p * 2 + 1] - qy)
                                    : ((cp[p * 2] - qx) * 2304.f);
            } else if (e == 594) v = cl[0] * 48.f;
            else if (e == 595)   v = cl[1] * 48.f;
            else v = 0.f;
            tmp[j] = (_Float16)v;
        }
        *(int4*)&As[r * 64 + swz(r, c0)]     = *(int4*)&tmp[0];
        *(int4*)&As[r * 64 + swz(r, c0 + 8)] = *(int4*)&tmp[8];
        // ---- stage B tile (W0t chunk): 2048 groups of 8 f16, 8 per thread --
        #pragma unroll
        for (int i = 0; i < 8; i++) {
            int g = t * 8 + i;
            int br = g >> 3, bg = (g & 7) * 8;
            *(int4*)&Bs[br * 64 + swz(br, bg)] =
                *(const int4*)&W0t[(size_t)br * KPAD0 + k0 + bg];
        }
        __syncthreads();
        // ---- MFMA ----
        #pragma unroll
        for (int kk = 0; kk < 64; kk += 32) {
            f16x8 af[4], bf[4];
            #pragma unroll
            for (int mi = 0; mi < 4; mi++) {
                int ar = mi * 16 + lrow;
                af[mi] = *(const f16x8*)&As[ar * 64 + swz(ar, kk + lq * 8)];
            }
            #pragma unroll
            for (int ni = 0; ni < 4; ni++) {
                int br = wave * 64 + ni * 16 + lrow;
                bf[ni] = *(const f16x8*)&Bs[br * 64 + swz(br, kk + lq * 8)];
            }
            #pragma unroll
            for (int mi = 0; mi < 4; mi++)
                #pragma unroll
                for (int ni = 0; ni < 4; ni++)
                    acc[mi][ni] = __builtin_amdgcn_mfma_f32_16x16x32_f16(
                        af[mi], bf[ni], acc[mi][ni], 0, 0, 0);
        }
    }

    size_t crow0 = (size_t)blk * 64;
    #pragma unroll
    for (int mi = 0; mi < 4; mi++) {
        int rloc = mi * 16 + lq * 4;
        #pragma unroll
        for (int ni = 0; ni < 4; ni++) {
            int col = wave * 64 + ni * 16 + lrow;
            float bv = bias[col];
            #pragma unroll
            for (int rr = 0; rr < 4; rr++) {
                float v = acc[mi][ni][rr] + bv;
                v = v > 0.f ? v : 0.f;
                H[(crow0 + rloc + rr) * HID + col] = (_Float16)v;
            }
        }
    }
}

// ---------------- GEMM: C(M,N) = act(A(M,K) @ Bt(N,K)^T + bias) -------------
// 128x128 tile, BK=64, 256 threads = 4 waves (2x2), swizzled LDS.
template<bool RELU, typename OutT>
__global__ __launch_bounds__(256) void gemm_kernel(
    const _Float16* __restrict__ A, const _Float16* __restrict__ Bt,
    const float* __restrict__ bias, OutT* __restrict__ C,
    int Nout, int K, int ldc)
{
    __shared__ _Float16 As[128 * 64];
    __shared__ _Float16 Bs[128 * 64];
    int m0 = blockIdx.x * 128;
    int n0 = blockIdx.y * 128;
    int t = threadIdx.x;
    int wave = t >> 6, lane = t & 63;
    int wr = wave >> 1, wc = wave & 1;
    int lrow = lane & 15, lq = lane >> 4;

    f32x4 acc[4][4] = {};

    for (int k0 = 0; k0 < K; k0 += 64) {
        __syncthreads();
        #pragma unroll
        for (int i = 0; i < 4; i++) {
            int chunk = t + i * 256;
            int r = chunk >> 3, cc = (chunk & 7) * 8;
            *(int4*)&As[r * 64 + swz(r, cc)] = *(const int4*)&A[(size_t)(m0 + r) * K + k0 + cc];
            *(int4*)&Bs[r * 64 + swz(r, cc)] = *(const int4*)&Bt[(size_t)(n0 + r) * K + k0 + cc];
        }
        __syncthreads();
        #pragma unroll
        for (int kk = 0; kk < 64; kk += 32) {
            f16x8 af[4], bf[4];
            #pragma unroll
            for (int mi = 0; mi < 4; mi++) {
                int ar = wr * 64 + mi * 16 + lrow;
                af[mi] = *(const f16x8*)&As[ar * 64 + swz(ar, kk + lq * 8)];
            }
            #pragma unroll
            for (int ni = 0; ni < 4; ni++) {
                int br = wc * 64 + ni * 16 + lrow;
                bf[ni] = *(const f16x8*)&Bs[br * 64 + swz(br, kk + lq * 8)];
            }
            #pragma unroll
            for (int mi = 0; mi < 4; mi++)
                #pragma unroll
                for (int ni = 0; ni < 4; ni++)
                    acc[mi][ni] = __builtin_amdgcn_mfma_f32_16x16x32_f16(
                        af[mi], bf[ni], acc[mi][ni], 0, 0, 0);
        }
    }

    #pragma unroll
    for (int mi = 0; mi < 4; mi++) {
        int row = m0 + wr * 64 + mi * 16 + lq * 4;
        #pragma unroll
        for (int ni = 0; ni < 4; ni++) {
            int col = n0 + wc * 64 + ni * 16 + lrow;
            if (col < Nout) {
                float bv = bias[col];
                #pragma unroll
                for (int rr = 0; rr < 4; rr++) {
                    float v = acc[mi][ni][rr] + bv;
                    if (RELU) v = v > 0.f ? v : 0.f;
                    C[(size_t)(row + rr) * ldc + col] = (OutT)v;
                }
            }
        }
    }
}

// ---------------- combine: out = sum_s pred_s * (area_swap(s)/tot) ----------
__global__ void combine_kernel(const float* __restrict__ preds,
                               const float* __restrict__ areas,
                               float* __restrict__ out) {
    int idx = blockIdx.x * 256 + threadIdx.x;
    if (idx >= BQ * NOUT) return;
    int bq = idx / NOUT, o = idx - bq * NOUT;
    float a0 = areas[bq];
    float a1 = areas[BQ + bq];
    float a2 = areas[2 * BQ + bq];
    float a3 = areas[3 * BQ + bq];
    float tot = a0 + a1 + a2 + a3;
    size_t stride = (size_t)BQ * NOUT;
    float r = preds[0 * stride + (size_t)bq * NOUT + o] * a3
            + preds[1 * stride + (size_t)bq * NOUT + o] * a2
            + preds[2 * stride + (size_t)bq * NOUT + o] * a1
            + preds[3 * stride + (size_t)bq * NOUT + o] * a0;
    out[idx] = r / tot;
}

extern "C" void kernel_launch(void* const* d_in, const int* in_sizes, int n_in,
                              void* d_out, int out_size, void* d_ws, size_t ws_size,
                              hipStream_t stream) {
    const float* feat  = (const float*)d_in[0];
    const float* coord = (const float*)d_in[1];
    const float* cell  = (const float*)d_in[2];
    const float* w0 = (const float*)d_in[3];  const float* b0 = (const float*)d_in[4];
    const float* w1 = (const float*)d_in[5];  const float* b1 = (const float*)d_in[6];
    const float* w2 = (const float*)d_in[7];  const float* b2 = (const float*)d_in[8];
    const float* w3 = (const float*)d_in[9];  const float* b3 = (const float*)d_in[10];
    const float* w4 = (const float*)d_in[11]; const float* b4 = (const float*)d_in[12];
    float* out = (float*)d_out;

    char* ws = (char*)d_ws;
    size_t off = 0;
    _Float16* W0t = (_Float16*)(ws + off); off += (size_t)256 * KPAD0 * 2;
    _Float16* W1t = (_Float16*)(ws + off); off += (size_t)256 * 256 * 2;
    _Float16* W2t = (_Float16*)(ws + off); off += (size_t)256 * 256 * 2;
    _Float16* W3t = (_Float16*)(ws + off); off += (size_t)256 * 256 * 2;
    _Float16* W4t = (_Float16*)(ws + off); off += (size_t)128 * 256 * 2;
    float* areas  = (float*)(ws + off);    off += (size_t)4 * BQ * 4;
    float* preds  = (float*)(ws + off);    off += (size_t)4 * BQ * NOUT * 4;
    size_t fixed = off;

    // weights -> transposed f16
    {
        int n;
        n = 256 * KPAD0; transpose_cast<<<(n + 255) / 256, 256, 0, stream>>>(w0, W0t, 596, 256, KPAD0, 256);
        n = 256 * 256;   transpose_cast<<<(n + 255) / 256, 256, 0, stream>>>(w1, W1t, 256, 256, 256, 256);
        n = 256 * 256;   transpose_cast<<<(n + 255) / 256, 256, 0, stream>>>(w2, W2t, 256, 256, 256, 256);
        n = 256 * 256;   transpose_cast<<<(n + 255) / 256, 256, 0, stream>>>(w3, W3t, 256, 256, 256, 256);
        n = 128 * 256;   transpose_cast<<<(n + 255) / 256, 256, 0, stream>>>(w4, W4t, 256, NOUT, 256, 128);
    }

    size_t h_batched = (size_t)4 * BQ * HID * 2;   // 134 MB each
    bool batched = ws_size >= fixed + 2 * h_batched;

    if (batched) {
        _Float16* H0 = (_Float16*)(ws + fixed);
        _Float16* H1 = (_Float16*)(ws + fixed + h_batched);
        fused_gemm0<<<4096, 256, 0, stream>>>(feat, coord, cell, W0t, b0, areas, H0, 0);
        gemm_kernel<true, _Float16><<<dim3(2048, 2), 256, 0, stream>>>(H0, W1t, b1, H1, 256, 256, 256);
        gemm_kernel<true, _Float16><<<dim3(2048, 2), 256, 0, stream>>>(H1, W2t, b2, H0, 256, 256, 256);
        gemm_kernel<true, _Float16><<<dim3(2048, 2), 256, 0, stream>>>(H0, W3t, b3, H1, 256, 256, 256);
        gemm_kernel<false, float><<<dim3(2048, 1), 256, 0, stream>>>(H1, W4t, b4, preds, NOUT, 256, NOUT);
    } else {
        size_t h_single = (size_t)BQ * HID * 2;    // 33.5 MB each
        _Float16* H0 = (_Float16*)(ws + fixed);
        _Float16* H1 = (_Float16*)(ws + fixed + h_single);
        for (int s = 0; s < 4; s++) {
            fused_gemm0<<<1024, 256, 0, stream>>>(feat, coord, cell, W0t, b0, areas, H0, s);
            gemm_kernel<true, _Float16><<<dim3(512, 2), 256, 0, stream>>>(H0, W1t, b1, H1, 256, 256, 256);
            gemm_kernel<true, _Float16><<<dim3(512, 2), 256, 0, stream>>>(H1, W2t, b2, H0, 256, 256, 256);
            gemm_kernel<true, _Float16><<<dim3(512, 2), 256, 0, stream>>>(H0, W3t, b3, H1, 256, 256, 256);
            gemm_kernel<false, float><<<dim3(512, 1), 256, 0, stream>>>(
                H1, W4t, b4, preds + (size_t)s * BQ * NOUT, NOUT, 256, NOUT);
        }
    }

    combine_kernel<<<(BQ * NOUT + 255) / 256, 256, 0, stream>>>(preds, areas, out);
}

// Round 3
// 540.448 us; speedup vs baseline: 1.6281x; 1.6092x over previous
//
#include <hip/hip_runtime.h>
#include <hip/hip_bf16.h>

typedef _Float16 f16x8 __attribute__((ext_vector_type(8)));
typedef float f32x4 __attribute__((ext_vector_type(4)));

#define BQ 65536            // B*Q = 8*8192
#define KPAD0 640           // 596 -> 640; reordered: e' = pixel*64 + channel for e'<576
#define HID 256
#define NOUT 27

// XOR-swizzle for 64-f16-wide LDS rows (8 groups of 16B)
__device__ __forceinline__ int swz8(int r, int c) {
    return ((((c) >> 3) ^ ((r) & 7)) << 3) | ((c) & 7);
}
// XOR-swizzle for 256-f16-wide LDS rows (32 groups of 16B)
__device__ __forceinline__ int swz32(int r, int c) {
    return ((((c) >> 3) ^ ((r) & 31)) << 3) | ((c) & 7);
}

// async global->LDS 16B: lane's data lands at (wave-uniform base) + lane*16
__device__ __forceinline__ void gl_lds16(const _Float16* g, _Float16* l) {
    __builtin_amdgcn_global_load_lds(
        (const __attribute__((address_space(1))) void*)g,
        (__attribute__((address_space(3))) void*)l, 16, 0, 0);
}

// ---------------- feat (B,C,H,W) f32 -> featT (B,H,W,C) f16 -----------------
__global__ __launch_bounds__(256) void feat_transpose(
    const float* __restrict__ feat, _Float16* __restrict__ featT,
    _Float16* __restrict__ zbuf)
{
    __shared__ float tile[64 * 49];
    int bh = blockIdx.x;                 // 0..383 = b*48+h
    int b = bh / 48, h = bh - b * 48;
    int t = threadIdx.x;
    if (bh == 0 && t < 64) zbuf[t] = (_Float16)0.f;
    #pragma unroll
    for (int i = 0; i < 12; i++) {
        int idx = t + i * 256;           // < 3072
        int c = idx / 48, w = idx - c * 48;
        tile[c * 49 + w] = feat[(((size_t)b * 64 + c) * 48 + h) * 48 + w];
    }
    __syncthreads();
    #pragma unroll
    for (int i = 0; i < 12; i++) {
        int idx = t + i * 256;
        int w = idx >> 6, c = idx & 63;
        featT[(((size_t)b * 48 + h) * 48 + w) * 64 + c] = (_Float16)tile[c * 49 + w];
    }
}

// ---------------- weight transpose+cast: wt[n*Kpad+k] = w[k*Nin+n] ----------
__global__ void transpose_cast(const float* __restrict__ w, _Float16* __restrict__ wt,
                               int Kin, int Nin, int Kpad, int Npad) {
    int idx = blockIdx.x * 256 + threadIdx.x;
    if (idx >= Npad * Kpad) return;
    int n = idx / Kpad, k = idx - n * Kpad;
    float v = (n < Nin && k < Kin) ? w[k * Nin + n] : 0.f;
    wt[idx] = (_Float16)v;
}

// w0 with K-permutation: kp<576 -> src_k = (kp&63)*9 + (kp>>6)  (c*9+pixel)
__global__ void transpose_cast_w0(const float* __restrict__ w0, _Float16* __restrict__ wt) {
    int idx = blockIdx.x * 256 + threadIdx.x;
    if (idx >= 256 * KPAD0) return;
    int n = idx / KPAD0, kp = idx - n * KPAD0;
    int src = (kp < 576) ? ((kp & 63) * 9 + (kp >> 6)) : kp;
    float v = (src < 596) ? w0[src * 256 + n] : 0.f;
    wt[idx] = (_Float16)v;
}

// ---------------- megakernel: 64 rows x 4 shifts x 5 layers -----------------
__global__ __launch_bounds__(256) void mega(
    const _Float16* __restrict__ featT, const float* __restrict__ coord,
    const float* __restrict__ cell, const _Float16* __restrict__ zbuf,
    const _Float16* __restrict__ W0t, const _Float16* __restrict__ W1t,
    const _Float16* __restrict__ W2t, const _Float16* __restrict__ W3t,
    const _Float16* __restrict__ W4t,
    const float* __restrict__ b0, const float* __restrict__ b1,
    const float* __restrict__ b2, const float* __restrict__ b3,
    const float* __restrict__ b4, float* __restrict__ out)
{
    __shared__ _Float16 act[64 * 256];   // 32 KB activation tile (swz32)
    __shared__ _Float16 Bs[256 * 64];    // 32 KB weight staging (swz8)
    __shared__ _Float16 As[64 * 64];     // 8 KB layer0 input staging (swz8)
    __shared__ int   rc4[4][64][2];
    __shared__ float q4[4][64][2];
    __shared__ float area4[4][64];
    __shared__ float wgt[4][64];

    int t = threadIdx.x;
    int wave = t >> 6, lane = t & 63;
    int lrow = lane & 15, lq = lane >> 4;
    int bq0 = blockIdx.x * 64;

    // ---- prologue: centers / q-coords / areas / weights for all 4 shifts ----
    {
        int s = t >> 6, row = t & 63;
        int bq = bq0 + row;
        const float* cp = coord + (size_t)bq * 18;
        float vx = (s & 2) ? 1.f : -1.f, vy = (s & 1) ? 1.f : -1.f;
        float cx = cp[8] + vx * (1.f / 48.f) + 1e-6f;
        float cy = cp[9] + vy * (1.f / 48.f) + 1e-6f;
        cx = fminf(fmaxf(cx, -1.f + 1e-6f), 1.f - 1e-6f);
        cy = fminf(fmaxf(cy, -1.f + 1e-6f), 1.f - 1e-6f);
        int ri = (int)rintf((cx + 1.f) * 24.f - 0.5f); ri = min(max(ri, 0), 47);
        int ci = (int)rintf((cy + 1.f) * 24.f - 0.5f); ci = min(max(ci, 0), 47);
        float qx = (float)(2 * ri + 1) / 48.f - 1.f;
        float qy = (float)(2 * ci + 1) / 48.f - 1.f;
        rc4[s][row][0] = ri; rc4[s][row][1] = ci;
        q4[s][row][0] = qx;  q4[s][row][1] = qy;
        area4[s][row] = fabsf((cp[0] - qx) * 2304.f * (cp[1] - qy)) + 1e-9f;
    }
    __syncthreads();
    {
        int s = t >> 6, row = t & 63;
        float tot = area4[0][row] + area4[1][row] + area4[2][row] + area4[3][row];
        wgt[s][row] = area4[s ^ 3][row] / tot;
    }

    float outreg[4][2][4];
    #pragma unroll
    for (int mi = 0; mi < 4; mi++)
        #pragma unroll
        for (int ni = 0; ni < 2; ni++)
            #pragma unroll
            for (int rr = 0; rr < 4; rr++) outreg[mi][ni][rr] = 0.f;
    float bv4_0 = b4[lrow];
    float bv4_1 = (lrow < 11) ? b4[16 + lrow] : 0.f;

    for (int s = 0; s < 4; s++) {
        // ================= layer 0: K=640 (9 pixel chunks + rel/cell) =======
        f32x4 acc[4][4];
        #pragma unroll
        for (int mi = 0; mi < 4; mi++)
            #pragma unroll
            for (int ni = 0; ni < 4; ni++) acc[mi][ni] = (f32x4){0.f, 0.f, 0.f, 0.f};

        #pragma unroll
        for (int kp = 0; kp < 10; kp++) {
            __syncthreads();
            if (kp < 9) {
                const int di = kp / 3 - 1, dj = kp - (kp / 3) * 3 - 1;
                #pragma unroll
                for (int i2 = 0; i2 < 2; i2++) {
                    int si = i2 * 4 + wave;          // 8-row slab
                    int r = si * 8 + (lane >> 3);
                    int bq = bq0 + r, b = bq >> 13;
                    int ri = rc4[s][r][0] + di, ci = rc4[s][r][1] + dj;
                    const _Float16* src =
                        ((unsigned)ri < 48u && (unsigned)ci < 48u)
                            ? featT + ((((size_t)b * 48 + ri) * 48 + ci) << 6)
                            : zbuf;
                    int gs = (lane & 7) ^ (r & 7);
                    gl_lds16(src + gs * 8, &As[si * 8 * 64]);
                }
            } else {
                // rel(18) + cell(2) + pad
                int r = t >> 2, c0 = (t & 3) * 16;
                int bq = bq0 + r;
                const float* cp = coord + (size_t)bq * 18;
                float qx = q4[s][r][0], qy = q4[s][r][1];
                _Float16 tmp[16];
                #pragma unroll
                for (int j = 0; j < 16; j++) {
                    int idx = c0 + j;
                    float v;
                    if (idx < 18) v = (idx & 1) ? (cp[idx] - qy) : ((cp[idx] - qx) * 2304.f);
                    else if (idx == 18) v = cell[(size_t)bq * 2] * 48.f;
                    else if (idx == 19) v = cell[(size_t)bq * 2 + 1] * 48.f;
                    else v = 0.f;
                    tmp[j] = (_Float16)v;
                }
                *(int4*)&As[r * 64 + swz8(r, c0)]     = *(int4*)&tmp[0];
                *(int4*)&As[r * 64 + swz8(r, c0 + 8)] = *(int4*)&tmp[8];
            }
            // stage Bs: 256 rows x 64 cols of W0t at k-offset kp*64
            #pragma unroll
            for (int i2 = 0; i2 < 8; i2++) {
                int si = i2 * 4 + wave;
                int r = si * 8 + (lane >> 3);
                int gs = (lane & 7) ^ (r & 7);
                gl_lds16(W0t + (size_t)r * KPAD0 + kp * 64 + gs * 8, &Bs[si * 8 * 64]);
            }
            __syncthreads();
            #pragma unroll
            for (int kk = 0; kk < 64; kk += 32) {
                f16x8 af[4], bf[4];
                #pragma unroll
                for (int mi = 0; mi < 4; mi++) {
                    int ar = mi * 16 + lrow;
                    af[mi] = *(const f16x8*)&As[ar * 64 + swz8(ar, kk + lq * 8)];
                }
                #pragma unroll
                for (int ni = 0; ni < 4; ni++) {
                    int br = wave * 64 + ni * 16 + lrow;
                    bf[ni] = *(const f16x8*)&Bs[br * 64 + swz8(br, kk + lq * 8)];
                }
                #pragma unroll
                for (int mi = 0; mi < 4; mi++)
                    #pragma unroll
                    for (int ni = 0; ni < 4; ni++)
                        acc[mi][ni] = __builtin_amdgcn_mfma_f32_16x16x32_f16(
                            af[mi], bf[ni], acc[mi][ni], 0, 0, 0);
            }
        }
        // write act = relu(acc + b0)   (act not read during L0 -> no barrier)
        #pragma unroll
        for (int mi = 0; mi < 4; mi++) {
            int rbase = mi * 16 + lq * 4;
            #pragma unroll
            for (int ni = 0; ni < 4; ni++) {
                int col = wave * 64 + ni * 16 + lrow;
                float bv = b0[col];
                #pragma unroll
                for (int rr = 0; rr < 4; rr++) {
                    float v = acc[mi][ni][rr] + bv;
                    v = v > 0.f ? v : 0.f;
                    int r = rbase + rr;
                    act[r * 256 + swz32(r, col)] = (_Float16)v;
                }
            }
        }

        // ================= hidden layers 1..3 (K=256, N=256, in-place) ======
        for (int layer = 0; layer < 3; layer++) {
            const _Float16* Wl = (layer == 0) ? W1t : (layer == 1) ? W2t : W3t;
            const float*    bl = (layer == 0) ? b1  : (layer == 1) ? b2  : b3;
            #pragma unroll
            for (int mi = 0; mi < 4; mi++)
                #pragma unroll
                for (int ni = 0; ni < 4; ni++) acc[mi][ni] = (f32x4){0.f, 0.f, 0.f, 0.f};
            #pragma unroll
            for (int k0 = 0; k0 < 256; k0 += 64) {
                __syncthreads();
                #pragma unroll
                for (int i2 = 0; i2 < 8; i2++) {
                    int si = i2 * 4 + wave;
                    int r = si * 8 + (lane >> 3);
                    int gs = (lane & 7) ^ (r & 7);
                    gl_lds16(Wl + (size_t)r * 256 + k0 + gs * 8, &Bs[si * 8 * 64]);
                }
                __syncthreads();
                #pragma unroll
                for (int kk = 0; kk < 64; kk += 32) {
                    f16x8 af[4], bf[4];
                    #pragma unroll
                    for (int mi = 0; mi < 4; mi++) {
                        int ar = mi * 16 + lrow;
                        af[mi] = *(const f16x8*)&act[ar * 256 + swz32(ar, k0 + kk + lq * 8)];
                    }
                    #pragma unroll
                    for (int ni = 0; ni < 4; ni++) {
                        int br = wave * 64 + ni * 16 + lrow;
                        bf[ni] = *(const f16x8*)&Bs[br * 64 + swz8(br, kk + lq * 8)];
                    }
                    #pragma unroll
                    for (int mi = 0; mi < 4; mi++)
                        #pragma unroll
                        for (int ni = 0; ni < 4; ni++)
                            acc[mi][ni] = __builtin_amdgcn_mfma_f32_16x16x32_f16(
                                af[mi], bf[ni], acc[mi][ni], 0, 0, 0);
                }
            }
            __syncthreads();   // all act reads done before in-place overwrite
            #pragma unroll
            for (int mi = 0; mi < 4; mi++) {
                int rbase = mi * 16 + lq * 4;
                #pragma unroll
                for (int ni = 0; ni < 4; ni++) {
                    int col = wave * 64 + ni * 16 + lrow;
                    float bv = bl[col];
                    #pragma unroll
                    for (int rr = 0; rr < 4; rr++) {
                        float v = acc[mi][ni][rr] + bv;
                        v = v > 0.f ? v : 0.f;
                        int r = rbase + rr;
                        act[r * 256 + swz32(r, col)] = (_Float16)v;
                    }
                }
            }
        }

        // ================= final layer: N=128 (27 used), K=256 ==============
        f32x4 acc2[4][2];
        #pragma unroll
        for (int mi = 0; mi < 4; mi++)
            #pragma unroll
            for (int ni = 0; ni < 2; ni++) acc2[mi][ni] = (f32x4){0.f, 0.f, 0.f, 0.f};
        #pragma unroll
        for (int k0 = 0; k0 < 256; k0 += 64) {
            __syncthreads();
            #pragma unroll
            for (int i2 = 0; i2 < 4; i2++) {       // 128 rows
                int si = i2 * 4 + wave;
                int r = si * 8 + (lane >> 3);
                int gs = (lane & 7) ^ (r & 7);
                gl_lds16(W4t + (size_t)r * 256 + k0 + gs * 8, &Bs[si * 8 * 64]);
            }
            __syncthreads();
            if (wave < 2) {
                #pragma unroll
                for (int kk = 0; kk < 64; kk += 32) {
                    f16x8 af[4], bf[2];
                    #pragma unroll
                    for (int mi = 0; mi < 4; mi++) {
                        int ar = mi * 16 + lrow;
                        af[mi] = *(const f16x8*)&act[ar * 256 + swz32(ar, k0 + kk + lq * 8)];
                    }
                    #pragma unroll
                    for (int ni = 0; ni < 2; ni++) {
                        int br = wave * 64 + ni * 16 + lrow;
                        bf[ni] = *(const f16x8*)&Bs[br * 64 + swz8(br, kk + lq * 8)];
                    }
                    #pragma unroll
                    for (int mi = 0; mi < 4; mi++)
                        #pragma unroll
                        for (int ni = 0; ni < 2; ni++)
                            acc2[mi][ni] = __builtin_amdgcn_mfma_f32_16x16x32_f16(
                                af[mi], bf[ni], acc2[mi][ni], 0, 0, 0);
                }
            }
        }
        // weighted accumulation (wave 0 holds cols 0..31)
        if (wave == 0) {
            #pragma unroll
            for (int mi = 0; mi < 4; mi++)
                #pragma unroll
                for (int rr = 0; rr < 4; rr++) {
                    int row = mi * 16 + lq * 4 + rr;
                    float w = wgt[s][row];
                    outreg[mi][0][rr] += w * (acc2[mi][0][rr] + bv4_0);
                    outreg[mi][1][rr] += w * (acc2[mi][1][rr] + bv4_1);
                }
        }
    }

    if (wave == 0) {
        #pragma unroll
        for (int mi = 0; mi < 4; mi++)
            #pragma unroll
            for (int rr = 0; rr < 4; rr++) {
                int row = mi * 16 + lq * 4 + rr;
                size_t bq = (size_t)(bq0 + row);
                out[bq * 27 + lrow] = outreg[mi][0][rr];
                if (lrow < 11) out[bq * 27 + 16 + lrow] = outreg[mi][1][rr];
            }
    }
}

extern "C" void kernel_launch(void* const* d_in, const int* in_sizes, int n_in,
                              void* d_out, int out_size, void* d_ws, size_t ws_size,
                              hipStream_t stream) {
    const float* feat  = (const float*)d_in[0];
    const float* coord = (const float*)d_in[1];
    const float* cell  = (const float*)d_in[2];
    const float* w0 = (const float*)d_in[3];  const float* b0 = (const float*)d_in[4];
    const float* w1 = (const float*)d_in[5];  const float* b1 = (const float*)d_in[6];
    const float* w2 = (const float*)d_in[7];  const float* b2 = (const float*)d_in[8];
    const float* w3 = (const float*)d_in[9];  const float* b3 = (const float*)d_in[10];
    const float* w4 = (const float*)d_in[11]; const float* b4 = (const float*)d_in[12];
    float* out = (float*)d_out;

    char* ws = (char*)d_ws;
    size_t off = 0;
    _Float16* W0t = (_Float16*)(ws + off); off += (size_t)256 * KPAD0 * 2;
    _Float16* W1t = (_Float16*)(ws + off); off += (size_t)256 * 256 * 2;
    _Float16* W2t = (_Float16*)(ws + off); off += (size_t)256 * 256 * 2;
    _Float16* W3t = (_Float16*)(ws + off); off += (size_t)256 * 256 * 2;
    _Float16* W4t = (_Float16*)(ws + off); off += (size_t)128 * 256 * 2;
    _Float16* featT = (_Float16*)(ws + off); off += (size_t)8 * 48 * 48 * 64 * 2;
    _Float16* zbuf  = (_Float16*)(ws + off); off += 256;

    feat_transpose<<<8 * 48, 256, 0, stream>>>(feat, featT, zbuf);
    transpose_cast_w0<<<(256 * KPAD0 + 255) / 256, 256, 0, stream>>>(w0, W0t);
    transpose_cast<<<256, 256, 0, stream>>>(w1, W1t, 256, 256, 256, 256);
    transpose_cast<<<256, 256, 0, stream>>>(w2, W2t, 256, 256, 256, 256);
    transpose_cast<<<256, 256, 0, stream>>>(w3, W3t, 256, 256, 256, 256);
    transpose_cast<<<128, 256, 0, stream>>>(w4, W4t, 256, NOUT, 256, 128);

    mega<<<BQ / 64, 256, 0, stream>>>(featT, coord, cell, zbuf,
                                      W0t, W1t, W2t, W3t, W4t,
                                      b0, b1, b2, b3, b4, out);
}

// Round 4
// 457.426 us; speedup vs baseline: 1.9236x; 1.1815x over previous
//
#include <hip/hip_runtime.h>
#include <hip/hip_bf16.h>

typedef _Float16 f16x8 __attribute__((ext_vector_type(8)));
typedef float f32x4 __attribute__((ext_vector_type(4)));

#define BQ 65536            // B*Q = 8*8192
#define KPAD0 640           // W0t row stride; effective K = 608 (last 32 all-pad skipped)
#define HID 256
#define NOUT 27

// async global->LDS 16B: lane's data lands at (wave-uniform base) + lane*16
__device__ __forceinline__ void gl_lds16(const _Float16* g, _Float16* l) {
    __builtin_amdgcn_global_load_lds(
        (const __attribute__((address_space(1))) void*)g,
        (__attribute__((address_space(3))) void*)l, 16, 0, 0);
}

// ---------------- feat (B,C,H,W) f32 -> featT (B,H,W,C) f16 -----------------
__global__ __launch_bounds__(256) void feat_transpose(
    const float* __restrict__ feat, _Float16* __restrict__ featT,
    _Float16* __restrict__ zbuf)
{
    __shared__ float tile[64 * 49];
    int bh = blockIdx.x;                 // 0..383 = b*48+h
    int b = bh / 48, h = bh - b * 48;
    int t = threadIdx.x;
    if (bh == 0 && t < 128) zbuf[t] = (_Float16)0.f;
    #pragma unroll
    for (int i = 0; i < 12; i++) {
        int idx = t + i * 256;           // < 3072
        int c = idx / 48, w = idx - c * 48;
        tile[c * 49 + w] = feat[(((size_t)b * 64 + c) * 48 + h) * 48 + w];
    }
    __syncthreads();
    #pragma unroll
    for (int i = 0; i < 12; i++) {
        int idx = t + i * 256;
        int w = idx >> 6, c = idx & 63;
        featT[(((size_t)b * 48 + h) * 48 + w) * 64 + c] = (_Float16)tile[c * 49 + w];
    }
}

// ---------------- weight transpose+cast: wt[n*Kpad+k] = w[k*Nin+n] ----------
__global__ void transpose_cast(const float* __restrict__ w, _Float16* __restrict__ wt,
                               int Kin, int Nin, int Kpad, int Npad) {
    int idx = blockIdx.x * 256 + threadIdx.x;
    if (idx >= Npad * Kpad) return;
    int n = idx / Kpad, k = idx - n * Kpad;
    float v = (n < Nin && k < Kin) ? w[k * Nin + n] : 0.f;
    wt[idx] = (_Float16)v;
}

// w0 with K-permutation: kp<576 -> src_k = (kp&63)*9 + (kp>>6)  (pixel-major)
__global__ void transpose_cast_w0(const float* __restrict__ w0, _Float16* __restrict__ wt) {
    int idx = blockIdx.x * 256 + threadIdx.x;
    if (idx >= 256 * KPAD0) return;
    int n = idx / KPAD0, kp = idx - n * KPAD0;
    int src = (kp < 576) ? ((kp & 63) * 9 + (kp >> 6)) : kp;
    float v = (src < 596) ? w0[src * 256 + n] : 0.f;
    wt[idx] = (_Float16)v;
}

// ---------------- megakernel: one (64-row, shift) tile, 5 layers ------------
// grid = 4096: s = blk&3, bq0 = (blk>>2)*64. 256 thr = 4 waves (N-split).
// LDS ~49 KB -> 3 blocks/CU; launch_bounds(256,3) caps VGPR <= ~170.
__global__ __launch_bounds__(256, 3) void mega(
    const _Float16* __restrict__ featT, const float* __restrict__ coord,
    const float* __restrict__ cell, const _Float16* __restrict__ zbuf,
    const _Float16* __restrict__ W0t, const _Float16* __restrict__ W1t,
    const _Float16* __restrict__ W2t, const _Float16* __restrict__ W3t,
    const _Float16* __restrict__ W4t,
    const float* __restrict__ b0, const float* __restrict__ b1,
    const float* __restrict__ b2, const float* __restrict__ b3,
    const float* __restrict__ b4, float* __restrict__ out)
{
    __shared__ _Float16 act[64 * 256];   // 32 KB; first 4 KB doubles as As in L0
    __shared__ _Float16 Bs[256 * 32];    // 16 KB weight chunk (K-step 32)
    __shared__ int   rc_s[64][2];
    __shared__ float q_s[64][2];
    __shared__ float wgt[64];

    int t = threadIdx.x;
    int wave = t >> 6, lane = t & 63;
    int lrow = lane & 15, lq = lane >> 4;
    int blk = blockIdx.x;
    int s = blk & 3;
    int bq0 = (blk >> 2) * 64;
    _Float16* As = act;                  // alias: act dead during L0 K-loop

    // ---- prologue: this shift's rc/q + all-4 areas -> blend weight ----------
    if (t < 64) {
        int bq = bq0 + t;
        const float* cp = coord + (size_t)bq * 18;
        float areas[4]; int mri = 0, mci = 0; float mqx = 0.f, mqy = 0.f;
        #pragma unroll
        for (int ss = 0; ss < 4; ss++) {
            float vx = (ss & 2) ? 1.f : -1.f, vy = (ss & 1) ? 1.f : -1.f;
            float cx = cp[8] + vx * (1.f / 48.f) + 1e-6f;
            float cy = cp[9] + vy * (1.f / 48.f) + 1e-6f;
            cx = fminf(fmaxf(cx, -1.f + 1e-6f), 1.f - 1e-6f);
            cy = fminf(fmaxf(cy, -1.f + 1e-6f), 1.f - 1e-6f);
            int ri = (int)rintf((cx + 1.f) * 24.f - 0.5f); ri = min(max(ri, 0), 47);
            int ci = (int)rintf((cy + 1.f) * 24.f - 0.5f); ci = min(max(ci, 0), 47);
            float qx = (float)(2 * ri + 1) / 48.f - 1.f;
            float qy = (float)(2 * ci + 1) / 48.f - 1.f;
            areas[ss] = fabsf((cp[0] - qx) * 2304.f * (cp[1] - qy)) + 1e-9f;
            if (ss == s) { mri = ri; mci = ci; mqx = qx; mqy = qy; }
        }
        float tot = areas[0] + areas[1] + areas[2] + areas[3];
        wgt[t] = areas[s ^ 3] / tot;
        rc_s[t][0] = mri; rc_s[t][1] = mci;
        q_s[t][0] = mqx;  q_s[t][1] = mqy;
    }
    __syncthreads();

    // per-lane staging constants (row = wave*16 + lane>>2, swizzled src group)
    int srow = wave * 16 + (lane >> 2);
    int gdat = (lane & 3) ^ ((lane >> 3) & 3);
    int sbq  = bq0 + srow;
    int s_ri = rc_s[srow][0], s_ci = rc_s[srow][1];
    const _Float16* fbase = featT + ((size_t)(sbq >> 13)) * (48 * 48 * 64);

    float bv0 = b4[lrow];
    float bv1 = (lrow < 11) ? b4[16 + lrow] : 0.f;

    f32x4 acc[4][4];
    #pragma unroll
    for (int mi = 0; mi < 4; mi++)
        #pragma unroll
        for (int ni = 0; ni < 4; ni++) acc[mi][ni] = (f32x4){0.f, 0.f, 0.f, 0.f};

    // ================= layer 0: 19 K-steps of 32 =============================
    for (int p = 0; p < 9; p++) {
        int di = p / 3 - 1, dj = p - (p / 3) * 3 - 1;
        int r2 = s_ri + di, c2 = s_ci + dj;
        const _Float16* src = ((unsigned)r2 < 48u && (unsigned)c2 < 48u)
            ? fbase + (((size_t)r2 * 48 + c2) << 6) : zbuf;
        #pragma unroll
        for (int half = 0; half < 2; half++) {
            __syncthreads();
            gl_lds16(src + half * 32 + gdat * 8, &As[wave * 512]);
            int k0 = p * 64 + half * 32;
            #pragma unroll
            for (int j = 0; j < 4; j++) {
                int slab = j * 4 + wave;
                int br = slab * 16 + (lane >> 2);
                gl_lds16(W0t + (size_t)br * KPAD0 + k0 + gdat * 8, &Bs[slab * 512]);
            }
            __syncthreads();
            f16x8 af[4], bf[4];
            #pragma unroll
            for (int mi = 0; mi < 4; mi++) {
                int ar = mi * 16 + lrow;
                af[mi] = *(const f16x8*)&As[ar * 32 + ((lq ^ ((ar >> 1) & 3)) << 3)];
            }
            #pragma unroll
            for (int ni = 0; ni < 4; ni++) {
                int br = wave * 64 + ni * 16 + lrow;
                bf[ni] = *(const f16x8*)&Bs[br * 32 + ((lq ^ ((br >> 1) & 3)) << 3)];
            }
            #pragma unroll
            for (int mi = 0; mi < 4; mi++)
                #pragma unroll
                for (int ni = 0; ni < 4; ni++)
                    acc[mi][ni] = __builtin_amdgcn_mfma_f32_16x16x32_f16(
                        af[mi], bf[ni], acc[mi][ni], 0, 0, 0);
        }
    }
    {   // rel/cell chunk: k0 = 576
        __syncthreads();
        int r = t >> 2, c0 = (t & 3) * 8;
        int bq = bq0 + r;
        const float* cp2 = coord + (size_t)bq * 18;
        float qx = q_s[r][0], qy = q_s[r][1];
        _Float16 tmp[8];
        #pragma unroll
        for (int j = 0; j < 8; j++) {
            int idx = c0 + j;
            float v;
            if (idx < 18) v = (idx & 1) ? (cp2[idx] - qy) : ((cp2[idx] - qx) * 2304.f);
            else if (idx == 18) v = cell[(size_t)bq * 2] * 48.f;
            else if (idx == 19) v = cell[(size_t)bq * 2 + 1] * 48.f;
            else v = 0.f;
            tmp[j] = (_Float16)v;
        }
        int gslot = ((c0 >> 3) ^ ((r >> 1) & 3)) & 3;
        *(int4*)&As[r * 32 + gslot * 8] = *(int4*)&tmp[0];
        #pragma unroll
        for (int j = 0; j < 4; j++) {
            int slab = j * 4 + wave;
            int br = slab * 16 + (lane >> 2);
            gl_lds16(W0t + (size_t)br * KPAD0 + 576 + gdat * 8, &Bs[slab * 512]);
        }
        __syncthreads();
        f16x8 af[4], bf[4];
        #pragma unroll
        for (int mi = 0; mi < 4; mi++) {
            int ar = mi * 16 + lrow;
            af[mi] = *(const f16x8*)&As[ar * 32 + ((lq ^ ((ar >> 1) & 3)) << 3)];
        }
        #pragma unroll
        for (int ni = 0; ni < 4; ni++) {
            int br = wave * 64 + ni * 16 + lrow;
            bf[ni] = *(const f16x8*)&Bs[br * 32 + ((lq ^ ((br >> 1) & 3)) << 3)];
        }
        #pragma unroll
        for (int mi = 0; mi < 4; mi++)
            #pragma unroll
            for (int ni = 0; ni < 4; ni++)
                acc[mi][ni] = __builtin_amdgcn_mfma_f32_16x16x32_f16(
                    af[mi], bf[ni], acc[mi][ni], 0, 0, 0);
    }
    __syncthreads();   // As reads done before act epilogue writes
    {   // act = relu(acc + b0)
        float bvv[4];
        #pragma unroll
        for (int ni = 0; ni < 4; ni++) bvv[ni] = b0[wave * 64 + ni * 16 + lrow];
        #pragma unroll
        for (int mi = 0; mi < 4; mi++)
            #pragma unroll
            for (int ni = 0; ni < 4; ni++) {
                int cw = wave * 64 + ni * 16 + lrow;
                #pragma unroll
                for (int rr = 0; rr < 4; rr++) {
                    float v = acc[mi][ni][rr] + bvv[ni];
                    v = v > 0.f ? v : 0.f;
                    int rw = mi * 16 + lq * 4 + rr;
                    int gp = ((cw >> 3) ^ (rw & 31)) & 31;
                    act[rw * 256 + gp * 8 + (cw & 7)] = (_Float16)v;
                }
            }
    }

    // ================= hidden layers 1..3 (K=256, N=256, in-place) ===========
    for (int layer = 0; layer < 3; layer++) {
        const _Float16* Wl = (layer == 0) ? W1t : (layer == 1) ? W2t : W3t;
        const float*    bl = (layer == 0) ? b1  : (layer == 1) ? b2  : b3;
        #pragma unroll
        for (int mi = 0; mi < 4; mi++)
            #pragma unroll
            for (int ni = 0; ni < 4; ni++) acc[mi][ni] = (f32x4){0.f, 0.f, 0.f, 0.f};
        #pragma unroll 2
        for (int k0 = 0; k0 < 256; k0 += 32) {
            __syncthreads();
            #pragma unroll
            for (int j = 0; j < 4; j++) {
                int slab = j * 4 + wave;
                int br = slab * 16 + (lane >> 2);
                gl_lds16(Wl + (size_t)br * 256 + k0 + gdat * 8, &Bs[slab * 512]);
            }
            __syncthreads();
            f16x8 af[4], bf[4];
            #pragma unroll
            for (int mi = 0; mi < 4; mi++) {
                int ar = mi * 16 + lrow;
                int gp = (((k0 >> 3) + lq) ^ (ar & 31)) & 31;
                af[mi] = *(const f16x8*)&act[ar * 256 + gp * 8];
            }
            #pragma unroll
            for (int ni = 0; ni < 4; ni++) {
                int br = wave * 64 + ni * 16 + lrow;
                bf[ni] = *(const f16x8*)&Bs[br * 32 + ((lq ^ ((br >> 1) & 3)) << 3)];
            }
            #pragma unroll
            for (int mi = 0; mi < 4; mi++)
                #pragma unroll
                for (int ni = 0; ni < 4; ni++)
                    acc[mi][ni] = __builtin_amdgcn_mfma_f32_16x16x32_f16(
                        af[mi], bf[ni], acc[mi][ni], 0, 0, 0);
        }
        __syncthreads();   // all act reads done before in-place overwrite
        {
            float bvv[4];
            #pragma unroll
            for (int ni = 0; ni < 4; ni++) bvv[ni] = bl[wave * 64 + ni * 16 + lrow];
            #pragma unroll
            for (int mi = 0; mi < 4; mi++)
                #pragma unroll
                for (int ni = 0; ni < 4; ni++) {
                    int cw = wave * 64 + ni * 16 + lrow;
                    #pragma unroll
                    for (int rr = 0; rr < 4; rr++) {
                        float v = acc[mi][ni][rr] + bvv[ni];
                        v = v > 0.f ? v : 0.f;
                        int rw = mi * 16 + lq * 4 + rr;
                        int gp = ((cw >> 3) ^ (rw & 31)) & 31;
                        act[rw * 256 + gp * 8 + (cw & 7)] = (_Float16)v;
                    }
                }
        }
    }

    // ================= final layer: N=32 (27 used), K=256 ====================
    f32x4 acc2[4][2];
    #pragma unroll
    for (int mi = 0; mi < 4; mi++)
        #pragma unroll
        for (int ni = 0; ni < 2; ni++) acc2[mi][ni] = (f32x4){0.f, 0.f, 0.f, 0.f};
    #pragma unroll 2
    for (int k0 = 0; k0 < 256; k0 += 32) {
        __syncthreads();
        if (wave < 2) {
            int br = wave * 16 + (lane >> 2);
            gl_lds16(W4t + (size_t)br * 256 + k0 + gdat * 8, &Bs[wave * 512]);
        }
        __syncthreads();
        if (wave == 0) {
            f16x8 af[4], bf[2];
            #pragma unroll
            for (int mi = 0; mi < 4; mi++) {
                int ar = mi * 16 + lrow;
                int gp = (((k0 >> 3) + lq) ^ (ar & 31)) & 31;
                af[mi] = *(const f16x8*)&act[ar * 256 + gp * 8];
            }
            #pragma unroll
            for (int ni = 0; ni < 2; ni++) {
                int br = ni * 16 + lrow;
                bf[ni] = *(const f16x8*)&Bs[br * 32 + ((lq ^ ((br >> 1) & 3)) << 3)];
            }
            #pragma unroll
            for (int mi = 0; mi < 4; mi++)
                #pragma unroll
                for (int ni = 0; ni < 2; ni++)
                    acc2[mi][ni] = __builtin_amdgcn_mfma_f32_16x16x32_f16(
                        af[mi], bf[ni], acc2[mi][ni], 0, 0, 0);
        }
    }

    // weighted atomic accumulation into out (zeroed by host-side memset)
    if (wave == 0) {
        #pragma unroll
        for (int mi = 0; mi < 4; mi++)
            #pragma unroll
            for (int rr = 0; rr < 4; rr++) {
                int row = mi * 16 + lq * 4 + rr;
                float w = wgt[row];
                size_t obase = (size_t)(bq0 + row) * 27;
                atomicAdd(&out[obase + lrow], w * (acc2[mi][0][rr] + bv0));
                if (lrow < 11)
                    atomicAdd(&out[obase + 16 + lrow], w * (acc2[mi][1][rr] + bv1));
            }
    }
}

extern "C" void kernel_launch(void* const* d_in, const int* in_sizes, int n_in,
                              void* d_out, int out_size, void* d_ws, size_t ws_size,
                              hipStream_t stream) {
    const float* feat  = (const float*)d_in[0];
    const float* coord = (const float*)d_in[1];
    const float* cell  = (const float*)d_in[2];
    const float* w0 = (const float*)d_in[3];  const float* b0 = (const float*)d_in[4];
    const float* w1 = (const float*)d_in[5];  const float* b1 = (const float*)d_in[6];
    const float* w2 = (const float*)d_in[7];  const float* b2 = (const float*)d_in[8];
    const float* w3 = (const float*)d_in[9];  const float* b3 = (const float*)d_in[10];
    const float* w4 = (const float*)d_in[11]; const float* b4 = (const float*)d_in[12];
    float* out = (float*)d_out;

    char* ws = (char*)d_ws;
    size_t off = 0;
    _Float16* W0t = (_Float16*)(ws + off); off += (size_t)256 * KPAD0 * 2;
    _Float16* W1t = (_Float16*)(ws + off); off += (size_t)256 * 256 * 2;
    _Float16* W2t = (_Float16*)(ws + off); off += (size_t)256 * 256 * 2;
    _Float16* W3t = (_Float16*)(ws + off); off += (size_t)256 * 256 * 2;
    _Float16* W4t = (_Float16*)(ws + off); off += (size_t)32 * 256 * 2;
    _Float16* featT = (_Float16*)(ws + off); off += (size_t)8 * 48 * 48 * 64 * 2;
    _Float16* zbuf  = (_Float16*)(ws + off); off += 512;

    hipMemsetAsync(d_out, 0, (size_t)BQ * NOUT * sizeof(float), stream);

    feat_transpose<<<8 * 48, 256, 0, stream>>>(feat, featT, zbuf);
    transpose_cast_w0<<<(256 * KPAD0 + 255) / 256, 256, 0, stream>>>(w0, W0t);
    transpose_cast<<<256, 256, 0, stream>>>(w1, W1t, 256, 256, 256, 256);
    transpose_cast<<<256, 256, 0, stream>>>(w2, W2t, 256, 256, 256, 256);
    transpose_cast<<<256, 256, 0, stream>>>(w3, W3t, 256, 256, 256, 256);
    transpose_cast<<<32, 256, 0, stream>>>(w4, W4t, 256, NOUT, 256, 32);

    mega<<<4 * (BQ / 64), 256, 0, stream>>>(featT, coord, cell, zbuf,
                                            W0t, W1t, W2t, W3t, W4t,
                                            b0, b1, b2, b3, b4, out);
}